// Round 9
// baseline (29.230 us; speedup 1.0000x reference)
//
#include <hip/hip_runtime.h>
#include <math.h>

// Problem constants (fixed by setup_inputs)
#define RC_F    5.2f
#define INV_2RC 0.096153846f   // 1/(2*Rc): v_cos takes revolutions; cos(pi*d/Rc)=v_cos(d/(2*Rc))

typedef float f4 __attribute__((ext_vector_type(4)));
typedef float f2 __attribute__((ext_vector_type(2)));

// ---------------------------------------------------------------------------
// Lane-specialized fused kernel. Each wave owns 8 edges (8 lanes per edge).
//   Phase 1 (lanes 0-7 only):
//     - load the wave's 8 int2 connectivity pairs (one contiguous 64B segment)
//     - convert+store them to out_conn (one contiguous 64B store per wave)
//     - gather the two coord triplets (16B overlapping loads), compute d
//     - masked edge (-1) encoded as d = 1e30 (falls into the zero path)
//   Broadcast d to all lanes via one __shfl.
//   Phase 2 (all 64 lanes): q = lane&7 selects the (eta, shf-quad); each lane
//     computes one float4 quad of the 32-wide output row; lane-consecutive
//     float4 stores -> dense 1KB/wave, nontemporal.
// conn is fetched exactly once; gather request count cut 8x vs round 7.
// ---------------------------------------------------------------------------
__global__ __launch_bounds__(256) void APEV_fused(
    const int* __restrict__ conn,
    const float* __restrict__ coords,   // [B,256,3]
    const float* __restrict__ EtaR,     // [4]
    const float* __restrict__ ShfR,     // [8] (16B-aligned)
    float* __restrict__ out_conn,       // [N*2] as float
    float* __restrict__ y,              // [N,32]
    int n_edges)
{
    int t = blockIdx.x * 256 + threadIdx.x;
    int lane = threadIdx.x & 63;
    int gwave = t >> 6;                 // global wave id; wave owns 8 edges
    int ebase = gwave << 3;
    if (ebase >= n_edges) return;

    float dmine = 1e30f;                // sentinel: masked edge -> zero row
    if (lane < 8) {
        int e = ebase + lane;
        int2 cd = *reinterpret_cast<const int2*>(conn + (size_t)e * 2);

        // connectivity passthrough (8 lanes -> contiguous 64B per wave)
        f2 cf = { (float)cd.x, (float)cd.y };
        __builtin_nontemporal_store(cf, reinterpret_cast<f2*>(out_conn + (size_t)e * 2));

        if (cd.x != -1) {
            int b = e >> 15;            // E = 32768 edges per batch
            const float* pa = coords + ((size_t)(b << 8) + cd.x) * 3;
            const float* pd = coords + ((size_t)(b << 8) + cd.y) * 3;
            f4 va = *reinterpret_cast<const f4*>(pa);   // elem 3 unused
            f4 vd = *reinterpret_cast<const f4*>(pd);
            float dx = va.x - vd.x;
            float dy = va.y - vd.y;
            float dz = va.z - vd.z;
            dmine = __fsqrt_rn(dx * dx + dy * dy + dz * dz);
        }
    }
    // broadcast d of edge (lane>>3) from lane (lane>>3)
    float d = __shfl(dmine, lane >> 3, 64);

    int q = lane & 7;
    f4 res = { 0.f, 0.f, 0.f, 0.f };
    if (d <= RC_F) {
        // hardware cosine in revolutions; d/(2Rc) <= 0.5, in range
        float fc = 0.5f * __builtin_amdgcn_cosf(d * INV_2RC) + 0.5f;
        float eta = EtaR[q >> 1];
        f4 s = *reinterpret_cast<const f4*>(ShfR + ((q & 1) << 2));
        float c = 0.25f * fc;
        float t0 = d - s.x;
        float t1 = d - s.y;
        float t2 = d - s.z;
        float t3 = d - s.w;
        res.x = c * __expf(-eta * t0 * t0);
        res.y = c * __expf(-eta * t1 * t1);
        res.z = c * __expf(-eta * t2 * t2);
        res.w = c * __expf(-eta * t3 * t3);
    }

    int edge = ebase + (lane >> 3);
    __builtin_nontemporal_store(res, reinterpret_cast<f4*>(y + (size_t)edge * 32 + (q << 2)));
}

extern "C" void kernel_launch(void* const* d_in, const int* in_sizes, int n_in,
                              void* d_out, int out_size, void* d_ws, size_t ws_size,
                              hipStream_t stream) {
    const int*   conn   = (const int*)d_in[0];
    const float* coords = (const float*)d_in[1];
    const float* EtaR   = (const float*)d_in[2];
    const float* ShfR   = (const float*)d_in[3];

    float* out = (float*)d_out;

    const int n_conn_elems = in_sizes[0];      // B*E*2 = 2,097,152
    const int n_edges      = n_conn_elems / 2; // 1,048,576
    float* y = out + n_conn_elems;

    long long total = (long long)n_edges * 8;  // 8 threads per edge
    int blocks = (int)((total + 255) / 256);   // 32768

    APEV_fused<<<blocks, 256, 0, stream>>>(conn, coords, EtaR, ShfR,
                                           out, y, n_edges);
}

// Round 10
// 26.685 us; speedup vs baseline: 1.0954x; 1.0954x over previous
//
#include <hip/hip_runtime.h>
#include <math.h>

// Problem constants (fixed by setup_inputs)
#define RC_F    5.2f
#define INV_2RC 0.096153846f   // 1/(2*Rc): v_cos takes revolutions; cos(pi*d/Rc)=v_cos(d/(2*Rc))

typedef float f4 __attribute__((ext_vector_type(4)));

// ---------------------------------------------------------------------------
// Fused kernel (measured best: 26.95 us, ~88% of same-run fill BW).
//  - All blocks: radial terms, 8 threads per edge; each thread computes one
//    float4 quad of the 32-wide output row. Lane-consecutive float4 stores
//    -> fully coalesced 1 KB/wave, streamed nontemporally.
//  - Blocks [0, conn_blocks): additionally copy connectivity int32->float32,
//    one dense float4 per thread (fully-active wave store), nontemporal.
//  - Cosine via v_cos (revolutions); coords gathered as two overlapping 16B
//    loads (4B-aligned dwordx4 is legal) instead of 6 scalar loads.
// Rejected by measurement: q==0-lane fused conn store (r4, 29.4us),
// lane-specialized gather + __shfl broadcast (r9, 29.2us) — both trade the
// ~1.3us duplicate conn fetch for larger serialization/store-efficiency costs.
// ---------------------------------------------------------------------------
__global__ __launch_bounds__(256) void APEV_fused(
    const int* __restrict__ conn,
    const float* __restrict__ coords,   // [B,256,3]
    const float* __restrict__ EtaR,     // [4]
    const float* __restrict__ ShfR,     // [8] (16B-aligned)
    float* __restrict__ out_conn,       // [N*2] as float
    float* __restrict__ y,              // [N,32]
    int n_edges, int conn_blocks, int n_conn_elems)
{
    int t = blockIdx.x * 256 + threadIdx.x;

    // ---- connectivity passthrough (first conn_blocks blocks only) ----
    if (blockIdx.x < conn_blocks) {
        int i = t * 4;
        if (i < n_conn_elems) {
            int4 v = *reinterpret_cast<const int4*>(conn + i);
            f4 f = { (float)v.x, (float)v.y, (float)v.z, (float)v.w };
            __builtin_nontemporal_store(f, reinterpret_cast<f4*>(out_conn + i));
        }
    }

    // ---- radial terms ----
    int edge = t >> 3;
    if (edge >= n_edges) return;
    int q = t & 7;
    int b = edge >> 15;                 // E = 32768 = 2^15 edges per batch

    int2 cd = *reinterpret_cast<const int2*>(conn + (size_t)edge * 2);

    f4 res = { 0.f, 0.f, 0.f, 0.f };
    if (cd.x != -1) {
        // overlapping 16B gathers: element 3 of each is the neighbor's x, unused
        const float* pa = coords + ((size_t)(b << 8) + cd.x) * 3;
        const float* pd = coords + ((size_t)(b << 8) + cd.y) * 3;
        f4 va = *reinterpret_cast<const f4*>(pa);
        f4 vd = *reinterpret_cast<const f4*>(pd);
        float dx = va.x - vd.x;
        float dy = va.y - vd.y;
        float dz = va.z - vd.z;
        float d = __fsqrt_rn(dx * dx + dy * dy + dz * dz);

        if (d <= RC_F) {
            // hardware cosine in revolutions; d/(2Rc) <= 0.5, in range
            float fc = 0.5f * __builtin_amdgcn_cosf(d * INV_2RC) + 0.5f;
            float eta = EtaR[q >> 1];
            f4 s = *reinterpret_cast<const f4*>(ShfR + ((q & 1) << 2));
            float c = 0.25f * fc;
            float t0 = d - s.x;
            float t1 = d - s.y;
            float t2 = d - s.z;
            float t3 = d - s.w;
            res.x = c * __expf(-eta * t0 * t0);
            res.y = c * __expf(-eta * t1 * t1);
            res.z = c * __expf(-eta * t2 * t2);
            res.w = c * __expf(-eta * t3 * t3);
        }
    }

    __builtin_nontemporal_store(res, reinterpret_cast<f4*>(y + (size_t)edge * 32 + (q << 2)));
}

extern "C" void kernel_launch(void* const* d_in, const int* in_sizes, int n_in,
                              void* d_out, int out_size, void* d_ws, size_t ws_size,
                              hipStream_t stream) {
    const int*   conn   = (const int*)d_in[0];
    const float* coords = (const float*)d_in[1];
    const float* EtaR   = (const float*)d_in[2];
    const float* ShfR   = (const float*)d_in[3];

    float* out = (float*)d_out;

    const int n_conn_elems = in_sizes[0];      // B*E*2 = 2,097,152
    const int n_edges      = n_conn_elems / 2; // 1,048,576
    float* y = out + n_conn_elems;

    const int conn_blocks = (n_conn_elems / 4 + 255) / 256;   // 2048

    long long total = (long long)n_edges * 8;  // 8 threads per edge
    int blocks = (int)((total + 255) / 256);   // 32768

    APEV_fused<<<blocks, 256, 0, stream>>>(conn, coords, EtaR, ShfR,
                                           out, y, n_edges, conn_blocks,
                                           n_conn_elems);
}